// Round 4
// baseline (320.632 us; speedup 1.0000x reference)
//
#include <hip/hip_runtime.h>
#include <hip/hip_cooperative_groups.h>
#include <math.h>

namespace cg = cooperative_groups;

#define DD 5          // embedding dim
#define NFREQ 50      // frequencies per coordinate
#define NBLK 256      // grid blocks (co-resident: 1 block/CU)
#define NTHR 512      // threads per block (8 waves)

// ---------------------------------------------------------------- ragged self-attention helper
template <int SZ>
__device__ __forceinline__ void attn_group(const int* __restrict__ idx,
                                           float* __restrict__ emb) {
  int fid[SZ];
  float x[SZ][DD];
#pragma unroll
  for (int a = 0; a < SZ; ++a) {
    fid[a] = idx[a];
    const float* p = emb + (size_t)fid[a] * DD;
#pragma unroll
    for (int d = 0; d < DD; ++d) x[a][d] = p[d];
  }
  const float scale = rsqrtf((float)SZ);   // reference scales by sqrt(seq_len)
  float o[SZ][DD];
#pragma unroll
  for (int a = 0; a < SZ; ++a) {
    float sc[SZ];
    float m = -1e30f;
#pragma unroll
    for (int b = 0; b < SZ; ++b) {
      float dt = 0.f;
#pragma unroll
      for (int d = 0; d < DD; ++d) dt += x[a][d] * x[b][d];
      sc[b] = dt * scale;
      m = fmaxf(m, sc[b]);
    }
    float sum = 0.f;
#pragma unroll
    for (int b = 0; b < SZ; ++b) {
      sc[b] = __expf(sc[b] - m);
      sum += sc[b];
    }
    float inv = 1.f / sum;
#pragma unroll
    for (int d = 0; d < DD; ++d) {
      float acc = 0.f;
#pragma unroll
      for (int b = 0; b < SZ; ++b) acc += sc[b] * x[b][d];
      o[a][d] = acc * inv;
    }
  }
#pragma unroll
  for (int a = 0; a < SZ; ++a) {
    float* p = emb + (size_t)fid[a] * DD;
#pragma unroll
    for (int d = 0; d < DD; ++d) p[d] = o[a][d];
  }
}

// ---------------------------------------------------------------- mega kernel
__global__ __launch_bounds__(NTHR, 2) void mega_kernel(
    const float2* __restrict__ coords, const int* __restrict__ gm,
    const int* __restrict__ n2, int g2,
    const int* __restrict__ n3, int g3,
    const int* __restrict__ n4, int g4,
    const int* __restrict__ lci, const int* __restrict__ genes_oi,
    const float* __restrict__ W, const float* __restrict__ wexpr,
    const float* __restrict__ bias, float* __restrict__ out,
    float* __restrict__ emb, int* __restrict__ order, int* __restrict__ bc,
    int* __restrict__ starts, int* __restrict__ totals,
    int F, int n_genes, int chunk, int total4) {
  cg::grid_group grid = cg::this_grid();
  const int b = blockIdx.x;
  const int t = threadIdx.x;
  const int lane = t & 63;
  const int wv = t >> 6;                 // wave in block, 0..7
  const int gtid = b * NTHR + t;
  const int gstride = NBLK * NTHR;

  __shared__ int s_cnt[1000];            // hist counts, later scatter cursors
  __shared__ int s_starts[1001];
  __shared__ int s_wsum[8];
  __shared__ float s_freq[NFREQ];

  // ---- P1: per-block histogram of this block's contiguous chunk
  for (int j = t; j < n_genes; j += NTHR) s_cnt[j] = 0;
  __syncthreads();
  {
    int lo = b * chunk, hi = min(F, lo + chunk);
    for (int i = lo + t; i < hi; i += NTHR) atomicAdd(&s_cnt[gm[i]], 1);
  }
  __syncthreads();
  for (int j = t; j < n_genes; j += NTHR) bc[(size_t)j * NBLK + b] = s_cnt[j];

  grid.sync();

  // ---- P2: exclusive-scan each bin's NBLK block-counts (one wave per bin)
  {
    int bin = b * 8 + wv;
    if (bin < n_genes) {
      int* row = bc + (size_t)bin * NBLK;
      int4 v = ((int4*)row)[lane];       // lane holds entries 4l..4l+3
      int psum = v.x + v.y + v.z + v.w;
      int ip = psum;
#pragma unroll
      for (int off = 1; off < 64; off <<= 1) {
        int q = __shfl_up(ip, off);
        if (lane >= off) ip += q;
      }
      int base = ip - psum;              // exclusive prefix of this lane's chunk
      int4 e;
      e.x = base;
      e.y = base + v.x;
      e.z = e.y + v.y;
      e.w = e.z + v.z;
      ((int4*)row)[lane] = e;
      if (lane == 63) totals[bin] = ip;
    }
  }

  grid.sync();

  // ---- P3: every block scans bin totals -> s_starts (redundant, no extra sync)
  {
    int i0 = 2 * t, i1 = 2 * t + 1;
    int a0 = (i0 < n_genes) ? totals[i0] : 0;
    int a1 = (i1 < n_genes) ? totals[i1] : 0;
    int p = a0 + a1;
    int ip = p;
#pragma unroll
    for (int off = 1; off < 64; off <<= 1) {
      int q = __shfl_up(ip, off);
      if (lane >= off) ip += q;
    }
    if (lane == 63) s_wsum[wv] = ip;
    __syncthreads();
    if (t == 0) {
      int run = 0;
#pragma unroll
      for (int i = 0; i < 8; ++i) { int v = s_wsum[i]; s_wsum[i] = run; run += v; }
    }
    __syncthreads();
    int excl = s_wsum[wv] + (ip - p);    // exclusive prefix of pair (i0,i1)
    if (i0 < n_genes) s_starts[i0] = excl;
    if (i1 < n_genes) s_starts[i1] = excl + a0;
    if (i0 == n_genes) s_starts[n_genes] = excl;
    if (i1 == n_genes) s_starts[n_genes] = excl + a0;
    __syncthreads();
    if (b == 0)
      for (int j = t; j <= n_genes; j += NTHR) starts[j] = s_starts[j];
  }

  // ---- P4: scatter fragment ids by gene (LDS cursors, LDS atomics only)
  for (int j = t; j < n_genes; j += NTHR)
    s_cnt[j] = s_starts[j] + bc[(size_t)j * NBLK + b];
  __syncthreads();
  {
    int lo = b * chunk, hi = min(F, lo + chunk);
    for (int i = lo + t; i < hi; i += NTHR) {
      int g = gm[i];
      int p = atomicAdd(&s_cnt[g], 1);
      order[p] = i;
    }
  }

  grid.sync();

  // ---- P5: fragment embedding (2 genes per block concurrently; W via s_load)
  if (t < NFREQ) s_freq[t] = exp2f(-0.39863137f * (float)(t + 1));
  __syncthreads();
  {
    int h = b * 2 + (t >> 8);            // halfblock id, 0..511
    int tt = t & 255;
    for (int g = h; g < n_genes; g += NBLK * 2) {
      int gu = __builtin_amdgcn_readfirstlane(g);   // force wave-uniform
      int s0 = starts[gu];
      int s1 = starts[gu + 1];
      const float* __restrict__ Wg = W + (size_t)gu * (4 * NFREQ * DD);
      for (int i = s0 + tt; i < s1; i += 256) {
        int f = order[i];
        float2 xy = coords[f];
        float a0 = 0.f, a1 = 0.f, a2 = 0.f, a3 = 0.f, a4 = 0.f;
        for (int k = 0; k < NFREQ; ++k) {
          float fr = s_freq[k];
          float ax = xy.x * fr;
          float ay = xy.y * fr;
          float sx = __sinf(ax), cx = __cosf(ax);
          float sy = __sinf(ay), cy = __cosf(ay);
          const float* w0s = Wg + (2 * k) * DD;
          const float* w0c = w0s + DD;
          const float* w1s = Wg + (2 * NFREQ + 2 * k) * DD;
          const float* w1c = w1s + DD;
          a0 += sx * w0s[0] + cx * w0c[0] + sy * w1s[0] + cy * w1c[0];
          a1 += sx * w0s[1] + cx * w0c[1] + sy * w1s[1] + cy * w1c[1];
          a2 += sx * w0s[2] + cx * w0c[2] + sy * w1s[2] + cy * w1c[2];
          a3 += sx * w0s[3] + cx * w0c[3] + sy * w1s[3] + cy * w1c[3];
          a4 += sx * w0s[4] + cx * w0c[4] + sy * w1s[4] + cy * w1c[4];
        }
        float* e = emb + (size_t)f * DD;
        e[0] = 1.f / (1.f + __expf(-a0));
        e[1] = 1.f / (1.f + __expf(-a1));
        e[2] = 1.f / (1.f + __expf(-a2));
        e[3] = 1.f / (1.f + __expf(-a3));
        e[4] = 1.f / (1.f + __expf(-a4));
      }
    }
  }

  grid.sync();

  // ---- P6: ragged attention (in-place on emb) + output init (independent)
  {
    int gtot = g2 + g3 + g4;
    for (int w = gtid; w < gtot; w += gstride) {
      if (w < g2) attn_group<2>(n2 + (size_t)w * 2, emb);
      else if (w < g2 + g3) attn_group<3>(n3 + (size_t)(w - g2) * 3, emb);
      else attn_group<4>(n4 + (size_t)(w - g2 - g3) * 4, emb);
    }
    for (int v4 = gtid; v4 < total4; v4 += gstride) {
      int idx = v4 * 4;
      int j = idx % n_genes;             // n_genes % 4 == 0 -> same row
      float4 vv;
      vv.x = bias[genes_oi[j + 0]];
      vv.y = bias[genes_oi[j + 1]];
      vv.z = bias[genes_oi[j + 2]];
      vv.w = bias[genes_oi[j + 3]];
      reinterpret_cast<float4*>(out)[v4] = vv;
    }
  }

  grid.sync();

  // ---- P7: pooled projection scatter
  for (int f = gtid; f < F; f += gstride) {
    int ix = lci[f];
    int gcol = ix % n_genes;
    int g = genes_oi[gcol];
    const float* e = emb + (size_t)f * DD;
    const float* w = wexpr + (size_t)g * DD;
    float s = e[0] * w[0] + e[1] * w[1] + e[2] * w[2] + e[3] * w[3] + e[4] * w[4];
    atomicAdd(out + ix, s);
  }
}

// ---------------------------------------------------------------- launch
extern "C" void kernel_launch(void* const* d_in, const int* in_sizes, int n_in,
                              void* d_out, int out_size, void* d_ws, size_t ws_size,
                              hipStream_t stream) {
  const float2* coords  = (const float2*)d_in[0];
  const int* gm         = (const int*)d_in[1];
  const int* n2         = (const int*)d_in[2];
  const int* n3         = (const int*)d_in[3];
  const int* n4         = (const int*)d_in[4];
  const int* lci        = (const int*)d_in[5];
  const int* genes_oi   = (const int*)d_in[6];
  const float* W        = (const float*)d_in[7];
  const float* wexpr    = (const float*)d_in[8];
  const float* bias     = (const float*)d_in[9];
  float* out            = (float*)d_out;

  int F       = in_sizes[1];
  int n_genes = in_sizes[6];
  int g2 = in_sizes[2] / 2;
  int g3 = in_sizes[3] / 3;
  int g4 = in_sizes[4] / 4;

  char* ws = (char*)d_ws;
  size_t off = 0;
  float* emb   = (float*)(ws + off); off += (size_t)F * DD * sizeof(float);
  int* order   = (int*)(ws + off);   off += (size_t)F * sizeof(int);
  int* bc      = (int*)(ws + off);   off += (size_t)n_genes * NBLK * sizeof(int);
  int* starts  = (int*)(ws + off);   off += (size_t)(n_genes + 1) * sizeof(int);
  off = (off + 15) & ~(size_t)15;
  int* totals  = (int*)(ws + off);   off += (size_t)n_genes * sizeof(int);

  int chunk  = (F + NBLK - 1) / NBLK;
  int total4 = out_size / 4;

  void* args[] = {
    (void*)&coords, (void*)&gm,
    (void*)&n2, (void*)&g2, (void*)&n3, (void*)&g3, (void*)&n4, (void*)&g4,
    (void*)&lci, (void*)&genes_oi,
    (void*)&W, (void*)&wexpr, (void*)&bias, (void*)&out,
    (void*)&emb, (void*)&order, (void*)&bc, (void*)&starts, (void*)&totals,
    (void*)&F, (void*)&n_genes, (void*)&chunk, (void*)&total4
  };
  hipLaunchCooperativeKernel((void*)mega_kernel, dim3(NBLK), dim3(NTHR),
                             args, 0, stream);
}

// Round 5
// 142.864 us; speedup vs baseline: 2.2443x; 2.2443x over previous
//
#include <hip/hip_runtime.h>
#include <math.h>

#define DD 5          // embedding dim
#define NFREQ 50      // frequencies per coordinate
#define NB 128        // sort blocks
// ENC_DIM = 4*NFREQ = 200; W row per gene = 200*5 = 1000 floats

// ---------------------------------------------------------------- block-local histogram
// Each block histograms its contiguous chunk into LDS (depth ~1.5/bin), then
// writes per-block counts transposed: bc[bin*NB + b]. Also zeroes the ticket
// counter used by the next kernel (safe: kernel boundary orders it).
__global__ __launch_bounds__(256) void blockhist_kernel(
    const int* __restrict__ gm, int F, int chunk,
    int* __restrict__ bc, int n_genes, int* __restrict__ done) {
  __shared__ int cnt[1000];
  if (blockIdx.x == 0 && threadIdx.x == 0) *done = 0;
  for (int j = threadIdx.x; j < n_genes; j += blockDim.x) cnt[j] = 0;
  __syncthreads();
  int b = blockIdx.x;
  int lo = b * chunk;
  int hi = min(F, lo + chunk);
  for (int i = lo + threadIdx.x; i < hi; i += blockDim.x)
    atomicAdd(&cnt[gm[i]], 1);
  __syncthreads();
  for (int j = threadIdx.x; j < n_genes; j += blockDim.x)
    bc[j * NB + b] = cnt[j];
}

// ---------------------------------------------------------------- per-bin scan + starts
// One wave per bin (4 bins/block): exclusive-scan the bin's NB=128 block
// counts in-register (int2 + shfl), emit bin total. The LAST block to finish
// (device-atomic ticket) then scans the 1000 bin totals -> starts[].
__global__ __launch_bounds__(256) void binscan_starts_kernel(
    int* __restrict__ bc, int n_genes, int* __restrict__ totals,
    int* __restrict__ starts, int* __restrict__ done, int nblocks) {
  __shared__ int s_amlast;
  __shared__ int s_ws[4];
  int lane = threadIdx.x & 63;
  int wv = threadIdx.x >> 6;               // 0..3
  int bin = blockIdx.x * 4 + wv;
  if (bin < n_genes) {
    int2* row = (int2*)(bc + (size_t)bin * NB);   // 64 int2 per row
    int2 v = row[lane];
    int p = v.x + v.y;
    int ip = p;
#pragma unroll
    for (int off = 1; off < 64; off <<= 1) {
      int q = __shfl_up(ip, off);
      if (lane >= off) ip += q;
    }
    int base = ip - p;                      // exclusive prefix of this lane's pair
    int2 e;
    e.x = base;
    e.y = base + v.x;
    row[lane] = e;
    if (lane == 63) totals[bin] = ip;
  }
  __syncthreads();
  if (threadIdx.x == 0) {
    __threadfence();                        // publish totals
    int tk = atomicAdd(done, 1);
    s_amlast = (tk == nblocks - 1);
  }
  __syncthreads();
  if (!s_amlast) return;
  __threadfence();                          // acquire all totals
  // ---- scan 1000 totals with this block (n_genes % 4 == 0)
  int t = threadIdx.x;
  int4 v = make_int4(0, 0, 0, 0);
  if (4 * t < n_genes) v = ((const int4*)totals)[t];
  int p = v.x + v.y + v.z + v.w;
  int ip = p;
#pragma unroll
  for (int off = 1; off < 64; off <<= 1) {
    int q = __shfl_up(ip, off);
    if (lane >= off) ip += q;
  }
  if (lane == 63) s_ws[wv] = ip;
  __syncthreads();
  int add = 0;
#pragma unroll
  for (int i = 0; i < 4; ++i)
    if (i < wv) add += s_ws[i];
  int excl = add + ip - p;
  int4 e;
  e.x = excl;
  e.y = excl + v.x;
  e.z = e.y + v.y;
  e.w = e.z + v.z;
  if (4 * t < n_genes) ((int4*)starts)[t] = e;
  if (4 * t + 4 == n_genes) starts[n_genes] = e.w + v.w;   // grand total
}

// ---------------------------------------------------------------- scatter by gene
// LDS cursors seeded with this block's global offset per bin; LDS atomics only.
__global__ __launch_bounds__(256) void blockscatter_kernel(
    const int* __restrict__ gm, int F, int chunk,
    const int* __restrict__ bc, const int* __restrict__ starts,
    int* __restrict__ order, int n_genes) {
  __shared__ int cur[1000];
  int b = blockIdx.x;
  for (int j = threadIdx.x; j < n_genes; j += blockDim.x)
    cur[j] = starts[j] + bc[j * NB + b];
  __syncthreads();
  int lo = b * chunk;
  int hi = min(F, lo + chunk);
  for (int i = lo + threadIdx.x; i < hi; i += blockDim.x) {
    int g = gm[i];
    int p = atomicAdd(&cur[g], 1);
    order[p] = i;
  }
}

// ---------------------------------------------------------------- fragment embedding
// One block per gene: W addresses are wave-uniform -> scalar (SMEM) loads.
// Frequency table hoisted to LDS (saves 50 exp2f per fragment).
__global__ __launch_bounds__(256) void embed_kernel(
    const float2* __restrict__ coords, const int* __restrict__ order,
    const int* __restrict__ starts, const float* __restrict__ W,
    float* __restrict__ emb) {
  __shared__ float s_freq[NFREQ];
  if (threadIdx.x < NFREQ)
    s_freq[threadIdx.x] = exp2f(-0.39863137f * (float)(threadIdx.x + 1));
  __syncthreads();
  int g = blockIdx.x;
  int s0 = starts[g];
  int s1 = starts[g + 1];
  const float* __restrict__ Wg = W + (size_t)g * (4 * NFREQ * DD);

  for (int i = s0 + threadIdx.x; i < s1; i += blockDim.x) {
    int f = order[i];
    float2 xy = coords[f];
    float a0 = 0.f, a1 = 0.f, a2 = 0.f, a3 = 0.f, a4 = 0.f;
    for (int k = 0; k < NFREQ; ++k) {
      float fr = s_freq[k];
      float ax = xy.x * fr;
      float ay = xy.y * fr;
      float sx = __sinf(ax), cx = __cosf(ax);
      float sy = __sinf(ay), cy = __cosf(ay);
      const float* w0s = Wg + (2 * k) * DD;               // coord0 sin row
      const float* w0c = w0s + DD;                        // coord0 cos row
      const float* w1s = Wg + (2 * NFREQ + 2 * k) * DD;   // coord1 sin row
      const float* w1c = w1s + DD;                        // coord1 cos row
      a0 += sx * w0s[0] + cx * w0c[0] + sy * w1s[0] + cy * w1c[0];
      a1 += sx * w0s[1] + cx * w0c[1] + sy * w1s[1] + cy * w1c[1];
      a2 += sx * w0s[2] + cx * w0c[2] + sy * w1s[2] + cy * w1c[2];
      a3 += sx * w0s[3] + cx * w0c[3] + sy * w1s[3] + cy * w1c[3];
      a4 += sx * w0s[4] + cx * w0c[4] + sy * w1s[4] + cy * w1c[4];
    }
    float* e = emb + (size_t)f * DD;
    e[0] = 1.f / (1.f + __expf(-a0));
    e[1] = 1.f / (1.f + __expf(-a1));
    e[2] = 1.f / (1.f + __expf(-a2));
    e[3] = 1.f / (1.f + __expf(-a3));
    e[4] = 1.f / (1.f + __expf(-a4));
  }
}

// ---------------------------------------------------------------- ragged self-attention
template <int SZ>
__device__ __forceinline__ void attn_group(const int* __restrict__ idx,
                                           float* __restrict__ emb) {
  int fid[SZ];
  float x[SZ][DD];
#pragma unroll
  for (int a = 0; a < SZ; ++a) {
    fid[a] = idx[a];
    const float* p = emb + (size_t)fid[a] * DD;
#pragma unroll
    for (int d = 0; d < DD; ++d) x[a][d] = p[d];
  }
  const float scale = rsqrtf((float)SZ);   // reference scales by sqrt(seq_len)
  float o[SZ][DD];
#pragma unroll
  for (int a = 0; a < SZ; ++a) {
    float sc[SZ];
    float m = -1e30f;
#pragma unroll
    for (int b = 0; b < SZ; ++b) {
      float dt = 0.f;
#pragma unroll
      for (int d = 0; d < DD; ++d) dt += x[a][d] * x[b][d];
      sc[b] = dt * scale;
      m = fmaxf(m, sc[b]);
    }
    float sum = 0.f;
#pragma unroll
    for (int b = 0; b < SZ; ++b) {
      sc[b] = __expf(sc[b] - m);
      sum += sc[b];
    }
    float inv = 1.f / sum;
#pragma unroll
    for (int d = 0; d < DD; ++d) {
      float acc = 0.f;
#pragma unroll
      for (int b = 0; b < SZ; ++b) acc += sc[b] * x[b][d];
      o[a][d] = acc * inv;
    }
  }
#pragma unroll
  for (int a = 0; a < SZ; ++a) {
    float* p = emb + (size_t)fid[a] * DD;
#pragma unroll
    for (int d = 0; d < DD; ++d) p[d] = o[a][d];
  }
}

// ---------------------------------------------------------------- attention + out-init
// Independent writes (emb in-place vs out), both must precede pool.
__global__ __launch_bounds__(256) void attn_init_kernel(
    const int* __restrict__ n2, int g2,
    const int* __restrict__ n3, int g3,
    const int* __restrict__ n4, int g4,
    float* __restrict__ emb, float* __restrict__ out,
    const float* __restrict__ bias, const int* __restrict__ genes_oi,
    int n_genes, int total4) {
  int gtid = blockIdx.x * blockDim.x + threadIdx.x;
  int gs = gridDim.x * blockDim.x;
  int gtot = g2 + g3 + g4;
  for (int w = gtid; w < gtot; w += gs) {
    if (w < g2) attn_group<2>(n2 + (size_t)w * 2, emb);
    else if (w < g2 + g3) attn_group<3>(n3 + (size_t)(w - g2) * 3, emb);
    else attn_group<4>(n4 + (size_t)(w - g2 - g3) * 4, emb);
  }
  for (int v4 = gtid; v4 < total4; v4 += gs) {
    int idx = v4 * 4;
    int j = idx % n_genes;          // n_genes % 4 == 0 -> same row
    float4 vv;
    vv.x = bias[genes_oi[j + 0]];
    vv.y = bias[genes_oi[j + 1]];
    vv.z = bias[genes_oi[j + 2]];
    vv.w = bias[genes_oi[j + 3]];
    reinterpret_cast<float4*>(out)[v4] = vv;
  }
}

// ---------------------------------------------------------------- pooled projection scatter
// out[ix] += sum_d emb[f,d] * w_expr[genes_oi[ix % n_genes], d]
__global__ void pool_kernel(const float* __restrict__ emb, const int* __restrict__ lci,
                            const int* __restrict__ genes_oi,
                            const float* __restrict__ wexpr, int F, int n_genes,
                            float* __restrict__ out) {
  int t = blockIdx.x * blockDim.x + threadIdx.x;
  if (t >= F) return;
  int ix = lci[t];
  int gcol = ix % n_genes;
  int g = genes_oi[gcol];
  const float* e = emb + (size_t)t * DD;
  const float* w = wexpr + (size_t)g * DD;
  float s = e[0] * w[0] + e[1] * w[1] + e[2] * w[2] + e[3] * w[3] + e[4] * w[4];
  atomicAdd(out + ix, s);
}

// ---------------------------------------------------------------- launch
extern "C" void kernel_launch(void* const* d_in, const int* in_sizes, int n_in,
                              void* d_out, int out_size, void* d_ws, size_t ws_size,
                              hipStream_t stream) {
  const float2* coords  = (const float2*)d_in[0];
  const int* gm         = (const int*)d_in[1];
  const int* n2         = (const int*)d_in[2];
  const int* n3         = (const int*)d_in[3];
  const int* n4         = (const int*)d_in[4];
  const int* lci        = (const int*)d_in[5];
  const int* genes_oi   = (const int*)d_in[6];
  const float* W        = (const float*)d_in[7];
  const float* wexpr    = (const float*)d_in[8];
  const float* bias     = (const float*)d_in[9];
  float* out            = (float*)d_out;

  const int F       = in_sizes[1];
  const int n_genes = in_sizes[6];
  const int g2 = in_sizes[2] / 2;
  const int g3 = in_sizes[3] / 3;
  const int g4 = in_sizes[4] / 4;

  char* ws = (char*)d_ws;
  size_t off = 0;
  float* emb   = (float*)(ws + off); off += (size_t)F * DD * sizeof(float);
  int* order   = (int*)(ws + off);   off += (size_t)F * sizeof(int);
  int* bc      = (int*)(ws + off);   off += (size_t)n_genes * NB * sizeof(int);
  off = (off + 15) & ~(size_t)15;
  int* starts  = (int*)(ws + off);   off += (size_t)(n_genes + 4) * sizeof(int);
  off = (off + 15) & ~(size_t)15;
  int* totals  = (int*)(ws + off);   off += (size_t)n_genes * sizeof(int);
  int* done    = (int*)(ws + off);   off += 4 * sizeof(int);

  const int tb = 256;
  const int chunk = (F + NB - 1) / NB;

  blockhist_kernel<<<NB, tb, 0, stream>>>(gm, F, chunk, bc, n_genes, done);
  int scan_blocks = (n_genes + 3) / 4;    // one wave per bin, 4 bins/block
  binscan_starts_kernel<<<scan_blocks, tb, 0, stream>>>(bc, n_genes, totals,
                                                        starts, done, scan_blocks);
  blockscatter_kernel<<<NB, tb, 0, stream>>>(gm, F, chunk, bc, starts, order, n_genes);
  embed_kernel<<<n_genes, tb, 0, stream>>>(coords, order, starts, W, emb);
  int total4 = out_size / 4;
  attn_init_kernel<<<1250, tb, 0, stream>>>(n2, g2, n3, g3, n4, g4,
                                            emb, out, bias, genes_oi,
                                            n_genes, total4);
  pool_kernel<<<(F + tb - 1) / tb, tb, 0, stream>>>(emb, lci, genes_oi, wexpr,
                                                    F, n_genes, out);
}